// Round 9
// baseline (3001.768 us; speedup 1.0000x reference)
//
#include <hip/hip_runtime.h>
#include <hip/hip_fp16.h>

// ---------------------------------------------------------------------------
// 2-layer LSTM (T=512, B=128, H=512) + linear head, persistent-kernel design.
// Round 19: baseline (2318us) L1 UNCHANGED + restructured L2:
//  - waves 2/3 = dedicated flag POLLERS (h1/h2) publishing to LDS counters:
//    poll-detect latency for step t+1 overlaps step t's compute; compute
//    waves detect readiness with a ~50cy LDS spin instead of an LLC poll.
//  - kh-split eliminated: each compute wave (one per batch half) does full
//    K=1024: W_hh2 from register breg (as before) + W_ih2 from a one-time
//    64KB LDS preload (conflict-free ds_read_b128). No pbase exchange.
//  - ZERO barriers in the L2 loop: per-wave tile2 half + per-wave coalesced
//    ring2 store touch only own rows; release via LDS counter (r18-proven):
//    last wave (after own vmcnt drain) fires the unchanged 48-RMW release.
//  - ih2 MFMAs sit between h1 load and h2 spin -> overlap residual h2 wait.
//  - Fabric/flags/rings/pack/launch byte-identical to the 2318us baseline
//    (consumer-line flags, 48-RMW release, agent-scope ring atomics,
//    sc0sc1 lda16 with r17's "=&v" early-clobber fix). Bounded spins.
// ---------------------------------------------------------------------------

#define HDIM   512
#define TSTEPS 512
#define BATCH  128
#define DIN    5
#define NGRP   4
#define MGRP   32
#define NB1    16
#define NB2    32
#define RING   16
#define SPIN_CAP 16384

#define OFF_W1 0u            // packed layer1 weights: 16 blocks * 128KB = 2MB
#define OFF_W2 2097152u      // packed layer2 weights: 32 blocks * 128KB = 4MB
#define OFF_H1 6291456u      // h1 ring: 4 * 16 * 32 * 512 fp16 = 2MB
#define OFF_H2 8388608u      // h2 ring: 4 * 2 * 32 * 512 fp16 = 256KB
#define OFF_F1 8650752u      // flags1: 4 grp * 48 consumers * 128B = 24KB
#define OFF_F2 8675328u      // flags2: 4 grp * 48 consumers * 128B = 24KB
#define WS_END 8699904u
// flags1 consumer c: 0..15 = L1 block j ; 16..47 = L2 block j (h1)
// flags2 consumer c: 0..31 = L2 block j (h2) ; 32..47 = L1 block j (backpr.)
// Each consumer line: 32 u32 (128B); word p = producer p's cumulative count.

typedef _Float16 half8 __attribute__((ext_vector_type(8)));
typedef float    floatx4 __attribute__((ext_vector_type(4)));
typedef unsigned long long u64;

__device__ __forceinline__ float sigf(float v) { return 1.0f / (1.0f + __expf(-v)); }

__device__ __forceinline__ half8 as_h8(uint4 u) {
  union { uint4 u; half8 h; } c; c.u = u; return c.h;
}
__device__ __forceinline__ void ring_st8(_Float16* p, u64 v) {
  __hip_atomic_store((u64*)p, v, __ATOMIC_RELAXED, __HIP_MEMORY_SCOPE_AGENT);
}
__device__ __forceinline__ void flag_add(unsigned* p) {
  __hip_atomic_fetch_add(p, 1u, __ATOMIC_RELAXED, __HIP_MEMORY_SCOPE_AGENT);
}
// Poll ONE private consumer line: lane i (<n) reads word i; exit when all>=tgt.
__device__ __forceinline__ void poll_line(const unsigned* line, int n, unsigned tgt,
                                          int lane) {
  for (int it = 0; it < SPIN_CAP; ++it) {
    unsigned v = tgt;
    if (lane < n)
      v = __hip_atomic_load(line + lane, __ATOMIC_RELAXED, __HIP_MEMORY_SCOPE_AGENT);
    if (__all((int)(v >= tgt))) break;
  }
  __asm__ __volatile__("" ::: "memory");
}
// LDS helpers (workgroup scope) — r18-proven flavor.
__device__ __forceinline__ unsigned lds_add(unsigned* p) {
  return __hip_atomic_fetch_add(p, 1u, __ATOMIC_RELAXED, __HIP_MEMORY_SCOPE_WORKGROUP);
}
__device__ __forceinline__ unsigned lds_ld(const unsigned* p) {
  return __hip_atomic_load(p, __ATOMIC_RELAXED, __HIP_MEMORY_SCOPE_WORKGROUP);
}
__device__ __forceinline__ void lds_st(unsigned* p, unsigned v) {
  __hip_atomic_store(p, v, __ATOMIC_RELAXED, __HIP_MEMORY_SCOPE_WORKGROUP);
}
__device__ __forceinline__ void lds_spin(const unsigned* p, unsigned tgt) {
  for (int it = 0; it < SPIN_CAP; ++it)
    if (lds_ld(p) >= tgt) break;
  __asm__ __volatile__("" ::: "memory");
}
// 16 pipelined 16B agent-coherent loads (sc0 sc1), ONE waitcnt. "=&v": outputs
// must not overlap the %16 address pair (r17 fix for the r15/r16 faults).
__device__ __forceinline__ void lda16(const _Float16* p, uint4* a) {
  asm volatile(
      "global_load_dwordx4 %0, %16, off sc0 sc1\n\t"
      "global_load_dwordx4 %1, %16, off offset:64 sc0 sc1\n\t"
      "global_load_dwordx4 %2, %16, off offset:128 sc0 sc1\n\t"
      "global_load_dwordx4 %3, %16, off offset:192 sc0 sc1\n\t"
      "global_load_dwordx4 %4, %16, off offset:256 sc0 sc1\n\t"
      "global_load_dwordx4 %5, %16, off offset:320 sc0 sc1\n\t"
      "global_load_dwordx4 %6, %16, off offset:384 sc0 sc1\n\t"
      "global_load_dwordx4 %7, %16, off offset:448 sc0 sc1\n\t"
      "global_load_dwordx4 %8, %16, off offset:512 sc0 sc1\n\t"
      "global_load_dwordx4 %9, %16, off offset:576 sc0 sc1\n\t"
      "global_load_dwordx4 %10, %16, off offset:640 sc0 sc1\n\t"
      "global_load_dwordx4 %11, %16, off offset:704 sc0 sc1\n\t"
      "global_load_dwordx4 %12, %16, off offset:768 sc0 sc1\n\t"
      "global_load_dwordx4 %13, %16, off offset:832 sc0 sc1\n\t"
      "global_load_dwordx4 %14, %16, off offset:896 sc0 sc1\n\t"
      "global_load_dwordx4 %15, %16, off offset:960 sc0 sc1\n\t"
      "s_waitcnt vmcnt(0)"
      : "=&v"(a[0]), "=&v"(a[1]), "=&v"(a[2]), "=&v"(a[3]),
        "=&v"(a[4]), "=&v"(a[5]), "=&v"(a[6]), "=&v"(a[7]),
        "=&v"(a[8]), "=&v"(a[9]), "=&v"(a[10]), "=&v"(a[11]),
        "=&v"(a[12]), "=&v"(a[13]), "=&v"(a[14]), "=&v"(a[15])
      : "v"(p)
      : "memory");
}

// ---------------------------------------------------------------------------
extern "C" __global__ void init_kernel(char* __restrict__ ws, float* __restrict__ out,
                                       const float* __restrict__ blin) {
  unsigned tid = blockIdx.x * 256u + threadIdx.x;
  unsigned nz = (WS_END - OFF_H1) / 16u;
  if (tid < nz) ((uint4*)(ws + OFF_H1))[tid] = make_uint4(0, 0, 0, 0);
  if (tid < (unsigned)(BATCH * TSTEPS)) out[tid] = blin[0];
}

// Pack fp32 weights -> fp16 MFMA B-fragment layout (baseline, unchanged).
extern "C" __global__ void pack_kernel(const float* __restrict__ Whh1,
                                       const float* __restrict__ Wih2,
                                       const float* __restrict__ Whh2,
                                       char* __restrict__ ws) {
  unsigned tid = blockIdx.x * 256u + threadIdx.x;
  const float* src;
  char* dst;
  if (tid < 131072u) {
    unsigned lane = tid & 63u, ks = (tid >> 6) & 15u, gg = (tid >> 10) & 3u,
             h = (tid >> 12) & 1u, j = tid >> 13;
    unsigned cg = j * 32u + h * 16u + (lane & 15u);
    unsigned row = gg * 512u + cg;
    unsigned k0 = ks * 32u + (lane >> 4) * 8u;
    src = Whh1 + (size_t)row * 512u + k0;
    dst = ws + OFF_W1 + (size_t)tid * 16u;
  } else {
    unsigned t2 = tid - 131072u;
    if (t2 >= 262144u) return;
    unsigned lane = t2 & 63u, ksl = (t2 >> 6) & 15u, gg = (t2 >> 10) & 3u,
             kh = (t2 >> 12) & 1u, j = t2 >> 13;
    unsigned cg = j * 16u + (lane & 15u);
    unsigned row = gg * 512u + cg;
    unsigned kp = kh * 512u + ksl * 32u + (lane >> 4) * 8u;
    src = (kp < 512u) ? (Wih2 + (size_t)row * 512u + kp)
                      : (Whh2 + (size_t)row * 512u + (kp - 512u));
    dst = ws + OFF_W2 + (size_t)t2 * 16u;
  }
  float4 lo = ((const float4*)src)[0];
  float4 hi = ((const float4*)src)[1];
  _Float16 v[8] = {(_Float16)lo.x, (_Float16)lo.y, (_Float16)lo.z, (_Float16)lo.w,
                   (_Float16)hi.x, (_Float16)hi.y, (_Float16)hi.z, (_Float16)hi.w};
  *(uint4*)dst = *(const uint4*)v;
}

// ---------------------------------------------------------------------------
extern "C" __global__ __launch_bounds__(256, 1) void lstm_persist(
    const float* __restrict__ x,
    const float* __restrict__ Wih1,
    const float* __restrict__ bih1, const float* __restrict__ bhh1,
    const float* __restrict__ bih2, const float* __restrict__ bhh2,
    const float* __restrict__ Wlin,
    float* __restrict__ out,
    char* __restrict__ ws) {
  // L2 layout: [0,65536) ih2 weights; [65536,66560) tile2; [66560,66624) cnt.
  // L1 uses only the first 2KB (tile).
  __shared__ char smem[66624];
  unsigned* cnt = (unsigned*)(smem + 66560);
  // cnt[0] = store-count (2/step); cnt[1] = h2-visible; cnt[2] = h1-visible

  const int blk = blockIdx.x;
  const int xcd = blk & 7;
  const int slot = blk >> 3;
  const int tid = threadIdx.x;
  const int wave = tid >> 6;
  const int lane = tid & 63;
  const int nlane = lane & 15;
  const int quad = lane >> 4;

  _Float16* h1ring = (_Float16*)(ws + OFF_H1);
  _Float16* h2ring = (_Float16*)(ws + OFF_H2);

  if (xcd >= NGRP) {
    // --------------------- layer 1: BASELINE, UNCHANGED -------------------
    const int g = xcd - NGRP;
    const int j = slot;
    if (j >= NB1) return;
    const char* gW = ws + OFF_W1 + (size_t)j * 131072u;

    unsigned* f1g = (unsigned*)(ws + OFF_F1) + (size_t)g * 48 * 32;
    unsigned* f2g = (unsigned*)(ws + OFF_F2) + (size_t)g * 48 * 32;
    const unsigned* myline1 = f1g + (size_t)j * 32;         // 16 L1 producers
    const unsigned* mybp    = f2g + (size_t)(32 + j) * 32;  // 32 L2 producers
    _Float16* ring = h1ring + (size_t)g * (RING * MGRP * HDIM);
    _Float16* tile = (_Float16*)smem;  // 32x32 fp16 = 2KB

    const int mt = wave >> 1;  // batch half (16 rows)
    const int hh = wave & 1;   // column half (16 cols)
    const int cg = j * 32 + hh * 16 + nlane;

    half8 breg[64];
#pragma unroll
    for (int r = 0; r < 64; ++r)
      breg[r] = *(const half8*)(gW + (size_t)((hh * 64 + r) * 64 + lane) * 16);

    float bias_r[4], wih[4][5];
    for (int gg = 0; gg < 4; ++gg) {
      int row = gg * 512 + cg;
      bias_r[gg] = bih1[row] + bhh1[row];
      for (int k = 0; k < 5; ++k) wih[gg][k] = Wih1[row * 5 + k];
    }
    float cstate[4] = {};

    for (int t = 0; t < TSTEPS; ++t) {
      if (t) poll_line(myline1, NB1, (unsigned)t, lane);
      if ((t & 7) == 0 && t >= 16) poll_line(mybp, NB2, (unsigned)(t - 8), lane);

      const _Float16* ap =
          ring + (size_t)((t + RING - 1) & (RING - 1)) * (MGRP * HDIM) +
          mt * 16 * HDIM + nlane * HDIM + quad * 8;
      uint4 areg[16];
      lda16(ap, areg);

      float xr[4][5];
#pragma unroll
      for (int r = 0; r < 4; ++r) {
        int b = g * MGRP + mt * 16 + quad * 4 + r;
        const float* xp = x + ((size_t)t * BATCH + b) * DIN;
#pragma unroll
        for (int k = 0; k < 5; ++k) xr[r][k] = xp[k];
      }
      floatx4 acc[4];
#pragma unroll
      for (int gg = 0; gg < 4; ++gg) {
#pragma unroll
        for (int r = 0; r < 4; ++r) {
          float s = bias_r[gg];
#pragma unroll
          for (int k = 0; k < 5; ++k) s += xr[r][k] * wih[gg][k];
          acc[gg][r] = s;
        }
      }
#pragma unroll
      for (int ks = 0; ks < 16; ++ks) {
        half8 av = as_h8(areg[ks]);
#pragma unroll
        for (int gg = 0; gg < 4; ++gg)
          acc[gg] = __builtin_amdgcn_mfma_f32_16x16x32_f16(av, breg[gg * 16 + ks],
                                                           acc[gg], 0, 0, 0);
      }
#pragma unroll
      for (int r = 0; r < 4; ++r) {
        float iv = acc[0][r], fv = acc[1][r], gv = acc[2][r], ov = acc[3][r];
        float cn = sigf(fv) * cstate[r] + sigf(iv) * tanhf(gv);
        float hn = sigf(ov) * tanhf(cn);
        cstate[r] = cn;
        tile[(mt * 16 + quad * 4 + r) * 32 + hh * 16 + nlane] = (_Float16)hn;
      }
      __syncthreads();
      {
        _Float16* hout = ring + (size_t)(t & (RING - 1)) * (MGRP * HDIM);
        u64 v = *(const u64*)(tile + (tid >> 3) * 32 + (tid & 7) * 4);
        ring_st8(hout + (tid >> 3) * HDIM + j * 32 + (tid & 7) * 4, v);
      }
      __syncthreads();  // drains vmcnt: all stores globally visible
      if (tid < 48)
        flag_add(f1g + (size_t)tid * 32 + j);
    }
  } else {
    // --------------------- layer 2: poller-wave design --------------------
    const int g = xcd;
    const int j = slot;
    const char* gW = ws + OFF_W2 + (size_t)j * 131072u;

    unsigned* f1g = (unsigned*)(ws + OFF_F1) + (size_t)g * 48 * 32;
    unsigned* f2g = (unsigned*)(ws + OFF_F2) + (size_t)g * 48 * 32;
    const unsigned* l_h1 = f1g + (size_t)(16 + j) * 32;  // 16 L1 producers
    const unsigned* l_h2 = f2g + (size_t)j * 32;         // 32 L2 producers
    const _Float16* h1rd = h1ring + (size_t)g * (RING * MGRP * HDIM);
    _Float16* ring2 = h2ring + (size_t)g * (2 * MGRP * HDIM);
    const half8* wlds = (const half8*)smem;              // ih2 weights (64KB)
    _Float16* tile2 = (_Float16*)(smem + 65536);         // 32x16 fp16 = 1KB

    // one-time LDS preload of the W_ih2 slice (kh=0 half of packed block)
    {
      const uint4* src = (const uint4*)gW;   // first 64KB = kh0
      uint4* dst = (uint4*)smem;
#pragma unroll
      for (int i = 0; i < 16; ++i) dst[tid + i * 256] = src[tid + i * 256];
    }
    if (tid < 16) cnt[tid] = 0;
    __syncthreads();  // ONLY barrier in L2 (pre-loop)

    if (wave == 2) {
      // h2 poller: publish "flags2(line j) >= s" as cnt[1] = s
      for (unsigned s = 1; s < TSTEPS; ++s) {
        poll_line(l_h2, NB2, s, lane);
        if (lane == 0) lds_st(cnt + 1, s);
      }
      return;
    }
    if (wave == 3) {
      // h1 poller: publish "flags1(line 16+j) >= s" as cnt[2] = s
      for (unsigned s = 1; s <= TSTEPS; ++s) {
        poll_line(l_h1, NB1, s, lane);
        if (lane == 0) lds_st(cnt + 2, s);
      }
      return;
    }

    // compute waves 0,1: mt = wave (batch half), 16 cols, full K=1024
    const int mt = wave;
    const int cg = j * 16 + nlane;

    half8 breg[64];  // W_hh2 fragments (kh=1 half), register-resident
#pragma unroll
    for (int r = 0; r < 64; ++r)
      breg[r] = *(const half8*)(gW + 65536u + (size_t)(r * 64 + lane) * 16);

    float bias_r[4];
    for (int gg = 0; gg < 4; ++gg) {
      int row = gg * 512 + cg;
      bias_r[gg] = bih2[row] + bhh2[row];
    }
    const float wl = Wlin[cg];
    float cstate[4] = {};

    for (int t = 0; t < TSTEPS; ++t) {
      // h1(t) ready? (L1 runs ahead; LDS detect ~50cy)
      lds_spin(cnt + 2, (unsigned)(t + 1));
      const _Float16* ap1 = h1rd + (size_t)(t & (RING - 1)) * (MGRP * HDIM) +
                            mt * 16 * HDIM + nlane * HDIM + quad * 8;
      uint4 areg[16];
      lda16(ap1, areg);

      floatx4 acc[4];
#pragma unroll
      for (int gg = 0; gg < 4; ++gg)
        acc[gg] = (floatx4){bias_r[gg], bias_r[gg], bias_r[gg], bias_r[gg]};
      // ih2 part: B-fragments streamed from LDS (overlaps residual h2 wait)
#pragma unroll
      for (int ks = 0; ks < 16; ++ks) {
        half8 av = as_h8(areg[ks]);
#pragma unroll
        for (int gg = 0; gg < 4; ++gg)
          acc[gg] = __builtin_amdgcn_mfma_f32_16x16x32_f16(
              av, wlds[(size_t)(gg * 16 + ks) * 64 + lane], acc[gg], 0, 0, 0);
      }
      // h2(t-1) ready? (wave2 pre-polled during previous step's compute)
      if (t) lds_spin(cnt + 1, (unsigned)t);
      const _Float16* ap2 = ring2 + (size_t)((t + 1) & 1) * (MGRP * HDIM) +
                            mt * 16 * HDIM + nlane * HDIM + quad * 8;
      lda16(ap2, areg);
#pragma unroll
      for (int ks = 0; ks < 16; ++ks) {
        half8 av = as_h8(areg[ks]);
#pragma unroll
        for (int gg = 0; gg < 4; ++gg)
          acc[gg] = __builtin_amdgcn_mfma_f32_16x16x32_f16(av, breg[gg * 16 + ks],
                                                           acc[gg], 0, 0, 0);
      }
      // act -> own tile2 half (no cross-wave LDS dependency -> no barrier)
      float red[4];
#pragma unroll
      for (int r = 0; r < 4; ++r) {
        float iv = acc[0][r], fv = acc[1][r], gv = acc[2][r], ov = acc[3][r];
        float cn = sigf(fv) * cstate[r] + sigf(iv) * tanhf(gv);
        float hn = sigf(ov) * tanhf(cn);
        cstate[r] = cn;
        tile2[(mt * 16 + quad * 4 + r) * 16 + nlane] = (_Float16)hn;
        red[r] = wl * hn;
      }
      // own-half coalesced ring2 store (rows mt*16 + lane>>2)
      {
        int rl = lane >> 2, c4 = (lane & 3) * 4;
        asm volatile("s_waitcnt lgkmcnt(0)" ::: "memory");
        u64 v = *(const u64*)(tile2 + (mt * 16 + rl) * 16 + c4);
        ring_st8(ring2 + (size_t)(t & 1) * (MGRP * HDIM) +
                     (size_t)(mt * 16 + rl) * HDIM + j * 16 + c4, v);
      }
      asm volatile("s_waitcnt vmcnt(0)" ::: "memory");
      unsigned old = 0;
      if (lane == 0) old = lds_add(cnt);
      old = __shfl(old, 0, 64);
      if ((int)old == 2 * t + 1 && lane < 48)
        flag_add(f2g + (size_t)lane * 32 + j);  // 48-RMW release (baseline)
      // linear head: off the critical path
#pragma unroll
      for (int r = 0; r < 4; ++r) {
        float v2 = red[r];
        v2 += __shfl_xor(v2, 1, 64);
        v2 += __shfl_xor(v2, 2, 64);
        v2 += __shfl_xor(v2, 4, 64);
        v2 += __shfl_xor(v2, 8, 64);
        red[r] = v2;
      }
      if (nlane == 0) {
#pragma unroll
        for (int r = 0; r < 4; ++r) {
          int b = g * MGRP + mt * 16 + quad * 4 + r;
          atomicAdd(out + (size_t)b * TSTEPS + t, red[r]);
        }
      }
    }
  }
}

// ---------------------------------------------------------------------------
extern "C" void kernel_launch(void* const* d_in, const int* in_sizes, int n_in,
                              void* d_out, int out_size, void* d_ws, size_t ws_size,
                              hipStream_t stream) {
  const float* x    = (const float*)d_in[0];
  const float* Wih1 = (const float*)d_in[1];
  const float* Whh1 = (const float*)d_in[2];
  const float* bih1 = (const float*)d_in[3];
  const float* bhh1 = (const float*)d_in[4];
  const float* Wih2 = (const float*)d_in[5];
  const float* Whh2 = (const float*)d_in[6];
  const float* bih2 = (const float*)d_in[7];
  const float* bhh2 = (const float*)d_in[8];
  const float* Wlin = (const float*)d_in[9];
  const float* blin = (const float*)d_in[10];
  float* out = (float*)d_out;
  char* ws = (char*)d_ws;

  init_kernel<<<640, 256, 0, stream>>>(ws, out, blin);
  pack_kernel<<<1536, 256, 0, stream>>>(Whh1, Wih2, Whh2, ws);
  lstm_persist<<<256, 256, 0, stream>>>(x, Wih1, bih1, bhh1, bih2, bhh2, Wlin, out, ws);
}